// Round 6
// baseline (400.240 us; speedup 1.0000x reference)
//
#include <hip/hip_runtime.h>
#include <math.h>

#define N_    200
#define B_    512
#define K1_   100
#define K2_   50
#define ST    36     // sH row stride (dwords): 144B, 16B-aligned

// out layout: logp [512*2] | s1 [512*100] | s2 [512*50]
#define S1_OFF 1024
#define S2_OFF 52224

// workspace layout (bytes):
//        0 : gh    [512][200][32] f32  = 13,107,200
// 13107200 : gbits [512][200][8]  u32  =  3,276,800   (7 words used + pad)
#define WS_BITS_OFF 13107200

__device__ __forceinline__ float lrelu(float v) { return v > 0.f ? v : 0.2f * v; }
__device__ __forceinline__ float sigm(float v)  { return 1.f / (1.f + __expf(-v)); }

// ================= K1: high-occupancy x@W1 + adj ballot scan =================
// grid 2048: block = (graph g = bid>>2, chunk c = bid&3) -> nodes [c*50, c*50+50)
// no LDS, low VGPR -> 8 blocks/CU = 32 waves/CU
__global__ __launch_bounds__(256) void gnn_k1(
    const float* __restrict__ x, const float* __restrict__ adj,
    const float* __restrict__ W1, float* __restrict__ gh,
    unsigned* __restrict__ gbits)
{
  const int bid = blockIdx.x;
  const int g = bid >> 2, c = bid & 3;
  const int t = threadIdx.x;
  const int wv = t >> 6, ln = t & 63;
  const float* ag = adj + (size_t)g * N_ * N_;

  // ---- adj>0 bitmask via ballot: coalesced 64-lane row reads ----
  for (int r = wv; r < 50; r += 4) {
    int row = c * 50 + r;
    const float* arow = ag + row * N_;
    float a0 = arow[ln];
    float a1 = arow[64 + ln];
    float a2 = arow[128 + ln];
    float a3 = (ln < 8) ? arow[192 + ln] : -1.f;   // guard tensor OOB
    unsigned long long b0 = __ballot(a0 > 0.f);
    unsigned long long b1 = __ballot(a1 > 0.f);
    unsigned long long b2 = __ballot(a2 > 0.f);
    unsigned long long b3 = __ballot(a3 > 0.f);
    if (ln == 0) {
      unsigned* bp = gbits + (size_t)(g * N_ + row) * 8;
      *(uint4*)bp       = make_uint4((unsigned)b0, (unsigned)(b0 >> 32),
                                     (unsigned)b1, (unsigned)(b1 >> 32));
      *(uint4*)(bp + 4) = make_uint4((unsigned)b2, (unsigned)(b2 >> 32),
                                     (unsigned)b3, 0u);
    }
  }

  // ---- h = x @ W1 : thread = (node n, d-octet q); q is wave-uniform ----
  const int q = wv, n = t & 63;
  if (n < 50) {
    const int node = c * 50 + n;
    const float* xr = x + (size_t)g * N_ * N_ + node * N_;
    const float* Wq = W1 + q * 8;
    float acc[8];
    #pragma unroll
    for (int d = 0; d < 8; ++d) acc[d] = 0.f;
    for (int k = 0; k < N_; k += 4) {
      float4 xv = *(const float4*)(xr + k);
      #pragma unroll
      for (int kk = 0; kk < 4; ++kk) {
        float xs = (&xv.x)[kk];
        const float* wr = Wq + (k + kk) * 32;      // wave-uniform -> s_load
        #pragma unroll
        for (int d = 0; d < 8; ++d) acc[d] += xs * wr[d];
      }
    }
    float* hp = gh + (size_t)(g * N_ + node) * 32 + q * 8;
    *(float4*)hp       = make_float4(acc[0], acc[1], acc[2], acc[3]);
    *(float4*)(hp + 4) = make_float4(acc[4], acc[5], acc[6], acc[7]);
  }
}

// ================= K2: per-graph phases B..G, all-LDS =================
// LDS map (bytes), total 45264:
//     0 : sH    28800  h(200xST) stage; h1 in-place; rows 100..199 = sXK; h2a/h2 rows 0..99
// 28800 : sBITS  6400
// 35200 : sW2    4096
// 39296 : sMask2 2000
// 41296 : sES     800
// 42096 : sED     800
// 42896 : sKey   1024
// 43920 : sSel    400
// 44320 : sVal    400
// 44720 : sXV     512
// 45232 : sRed     32
__global__ __launch_bounds__(256) void gnn_k2(
    const float* __restrict__ gh, const unsigned* __restrict__ gbits,
    const float* __restrict__ a1s, const float* __restrict__ a1d,
    const float* __restrict__ b1,  const float* __restrict__ W2g,
    const float* __restrict__ a2s, const float* __restrict__ a2d,
    const float* __restrict__ b2,
    const float* __restrict__ pw1, const float* __restrict__ pw2,
    const float* __restrict__ fc1w, const float* __restrict__ fc1b,
    const float* __restrict__ fc2w, const float* __restrict__ fc2b,
    const float* __restrict__ fc3w, const float* __restrict__ fc3b,
    const float* __restrict__ bn4g, const float* __restrict__ bn4b,
    const float* __restrict__ bn5g, const float* __restrict__ bn5b,
    float* __restrict__ out)
{
  __shared__ __align__(16) char smem[45264];
  float*    sH    = (float*)smem;
  float*    sXK   = sH + 100 * ST;                 // rows 100..199 of sH
  unsigned* sBITS = (unsigned*)(smem + 28800);
  float*    sW2   = (float*)(smem + 35200);
  unsigned* sMask2= (unsigned*)(smem + 39296);
  float*    sES   = (float*)(smem + 41296);
  float*    sED   = (float*)(smem + 42096);
  float*    sKey  = (float*)(smem + 42896);
  int*      sSel  = (int*)(smem + 43920);
  float*    sVal  = (float*)(smem + 44320);
  float*    sXV   = (float*)(smem + 44720);
  float*    sRed  = (float*)(smem + 45232);

  const int t = threadIdx.x;
  const int b = blockIdx.x;

  // ---- stage h (1600 float4) and bits (1600 u32), coalesced; W2 fill ----
  {
    const float4* src = (const float4*)(gh + (size_t)b * N_ * 32);
    #pragma unroll
    for (int i = 0; i < 7; ++i) {
      int j = t + i * 256;
      if (j < 1600) {
        float4 v = src[j];
        int node = j >> 3, c4 = j & 7;
        *(float4*)&sH[node * ST + c4 * 4] = v;
      }
    }
    const unsigned* bsrc = gbits + (size_t)b * N_ * 8;
    #pragma unroll
    for (int i = 0; i < 7; ++i) {
      int j = t + i * 256;
      if (j < 1600) sBITS[j] = bsrc[j];
    }
    for (int i = t; i < 1024; i += 256) sW2[i] = W2g[i];
  }
  __syncthreads();

  // ---- es/ed from staged h ----
  if (t < N_) {
    float es = 0.f, ed = 0.f;
    #pragma unroll
    for (int c = 0; c < 8; ++c) {
      float4 hv = *(const float4*)&sH[t * ST + c * 4];
      es += hv.x * a1s[c*4+0] + hv.y * a1s[c*4+1] + hv.z * a1s[c*4+2] + hv.w * a1s[c*4+3];
      ed += hv.x * a1d[c*4+0] + hv.y * a1d[c*4+1] + hv.z * a1d[c*4+2] + hv.w * a1d[c*4+3];
    }
    sES[t] = es; sED[t] = ed;
  }
  __syncthreads();

  // esmax over all nodes (safe softmax bound; leaky_relu monotone)
  {
    float v = (t < N_) ? sES[t] : -3.0e38f;
    #pragma unroll
    for (int off = 1; off < 64; off <<= 1) v = fmaxf(v, __shfl_xor(v, off, 64));
    if ((t & 63) == 0) sRed[t >> 6] = v;
  }
  __syncthreads();
  {
    float esmax = fmaxf(fmaxf(sRed[0], sRed[1]), fmaxf(sRed[2], sRed[3]));

    // -------------- Phase B: sparse masked-softmax aggregate from bit masks --------------
    float acc[32];
    if (t < N_) {
      unsigned long long m0 = (unsigned long long)sBITS[t * 8 + 0] | ((unsigned long long)sBITS[t * 8 + 1] << 32);
      unsigned long long m1 = (unsigned long long)sBITS[t * 8 + 2] | ((unsigned long long)sBITS[t * 8 + 3] << 32);
      unsigned long long m2 = (unsigned long long)sBITS[t * 8 + 4] | ((unsigned long long)sBITS[t * 8 + 5] << 32);
      unsigned long long m3 = (unsigned long long)sBITS[t * 8 + 6];
      if (t < 64)       m0 |= 1ull << t;
      else if (t < 128) m1 |= 1ull << (t - 64);
      else if (t < 192) m2 |= 1ull << (t - 128);
      else              m3 |= 1ull << (t - 192);
      float ed_i = sED[t];
      float L = lrelu(ed_i + esmax);
      float ssum = 0.f;
      #pragma unroll
      for (int d = 0; d < 32; ++d) acc[d] = 0.f;
      #define AGG(mm, base)                                                        \
        while (mm) {                                                               \
          int j = (base) + (int)__builtin_ctzll(mm); mm &= (mm - 1);               \
          float w = __expf(lrelu(ed_i + sES[j]) - L); ssum += w;                   \
          const float* hr = &sH[j * ST];                                           \
          _Pragma("unroll")                                                        \
          for (int c = 0; c < 8; ++c) {                                            \
            float4 hv = *(const float4*)(hr + c * 4);                              \
            acc[c*4+0] += w * hv.x; acc[c*4+1] += w * hv.y;                        \
            acc[c*4+2] += w * hv.z; acc[c*4+3] += w * hv.w;                        \
          }                                                                        \
        }
      AGG(m0, 0) AGG(m1, 64) AGG(m2, 128) AGG(m3, 192)
      #undef AGG
      float inv = 1.f / ssum;
      #pragma unroll
      for (int d = 0; d < 32; ++d) acc[d] = acc[d] * inv + b1[d];
    }
    __syncthreads();                 // all reads of h done -> overwrite with h1
    if (t < N_) {
      #pragma unroll
      for (int d = 0; d < 32; ++d) sH[t * ST + d] = acc[d];
    }
  }
  __syncthreads();

  // -------------- Phase C: TopK pool 1 via barrier-free rank-select --------------
  {
    float npw = 0.f;
    #pragma unroll
    for (int d = 0; d < 32; ++d) npw += pw1[d] * pw1[d];
    npw = sqrtf(npw) + 1e-16f;
    float sc = -1.f;
    if (t < N_) {
      float dp = 0.f;
      #pragma unroll
      for (int d = 0; d < 32; ++d) dp += sH[t * ST + d] * pw1[d];
      sc = sigm(dp / npw);
    }
    sKey[t] = sc;
  }
  __syncthreads();
  if (t < N_) {
    float sc = sKey[t];
    int rank = 0;
    for (int j = 0; j < N_; j += 4) {
      #pragma unroll
      for (int jj = 0; jj < 4; ++jj) {
        float o = sKey[j + jj];                       // uniform -> broadcast
        rank += (o > sc || (o == sc && (j + jj) < t)) ? 1 : 0;
      }
    }
    if (rank < K1_) {                                 // stable desc order == lax.top_k
      sSel[rank] = t; sVal[rank] = sc;
      out[S1_OFF + b * K1_ + rank] = sc;
    }
  }
  __syncthreads();
  // xk = h1[sel]*val. Dest (sH rows 100..199) aliases source rows -> reg staging.
  {
    float tmp[13];
    #pragma unroll
    for (int it = 0; it < 13; ++it) {
      int i = t + it * 256;
      if (i < K1_ * 32) tmp[it] = sH[sSel[i >> 5] * ST + (i & 31)] * sVal[i >> 5];
    }
    __syncthreads();
    #pragma unroll
    for (int it = 0; it < 13; ++it) {
      int i = t + it * 256;
      if (i < K1_ * 32) sXK[(i >> 5) * ST + (i & 31)] = tmp[it];
    }
  }
  __syncthreads();
  // x1 = [max, mean] over 100 pooled nodes
  if (t < 32) {
    float m = -3.0e38f, s = 0.f;
    for (int r = 0; r < K1_; ++r) { float v = sXK[r * ST + t]; m = fmaxf(m, v); s += v; }
    sXV[t] = m; sXV[32 + t] = s / 100.f;
  }

  // -------------- Phase D: 2-hop mask (a2 != 0 | eye), boolean bitsets --------------
  if (t < K1_) {
    int gi = sSel[t];
    #pragma unroll
    for (int w = 0; w < 4; ++w) {
      unsigned m = 0;
      const int lim = (w < 3) ? 32 : 4;
      for (int jj = 0; jj < lim; ++jj) {
        int j = w * 32 + jj;
        int gj = sSel[j];
        unsigned bit = (sBITS[gi * 8 + (gj >> 5)] >> (gj & 31)) & 1u;
        if (j == t) bit = 1u;                       // (A+I) self loop
        m |= bit << jj;
      }
      sMask2[t * 5 + w] = m;
    }
  }
  __syncthreads();
  {
    unsigned pr0 = 0, pr1 = 0, pr2 = 0, pr3 = 0;
    if (t < K1_) {
      #pragma unroll
      for (int kw = 0; kw < 4; ++kw) {
        unsigned mk = sMask2[t * 5 + kw];
        const int lim = (kw < 3) ? 32 : 4;
        for (int kk = 0; kk < lim; ++kk) {
          if ((mk >> kk) & 1u) {
            int k = kw * 32 + kk;
            pr0 |= sMask2[k * 5 + 0]; pr1 |= sMask2[k * 5 + 1];
            pr2 |= sMask2[k * 5 + 2]; pr3 |= sMask2[k * 5 + 3];
          }
        }
      }
    }
    __syncthreads();
    if (t < K1_) {
      sMask2[t * 5 + 0] = pr0; sMask2[t * 5 + 1] = pr1;
      sMask2[t * 5 + 2] = pr2; sMask2[t * 5 + 3] = pr3;
    }
  }
  __syncthreads();

  // -------------- Phase E: GAT2 --------------
  // h2a = xk @ W2 -> sH rows 0..99 (h1 rows 0..99 dead; xk rows 100..199 untouched)
  if (t < K1_) {
    float xk[32];
    #pragma unroll
    for (int c = 0; c < 8; ++c) *(float4*)&xk[c * 4] = *(const float4*)&sXK[t * ST + c * 4];
    float acc2[32];
    #pragma unroll
    for (int d = 0; d < 32; ++d) acc2[d] = 0.f;
    #pragma unroll
    for (int k = 0; k < 32; ++k) {
      float xv = xk[k];
      const float* wr = &sW2[k * 32];
      #pragma unroll
      for (int d = 0; d < 32; ++d) acc2[d] += xv * wr[d];
    }
    float es = 0.f, ed = 0.f;
    #pragma unroll
    for (int d = 0; d < 32; ++d) { es += acc2[d] * a2s[d]; ed += acc2[d] * a2d[d]; }
    sES[t] = es; sED[t] = ed;
    #pragma unroll
    for (int d = 0; d < 32; ++d) sH[t * ST + d] = acc2[d];
  }
  __syncthreads();
  {
    float v = (t < K1_) ? sES[t] : -3.0e38f;
    #pragma unroll
    for (int off = 1; off < 64; off <<= 1) v = fmaxf(v, __shfl_xor(v, off, 64));
    if ((t & 63) == 0) sRed[t >> 6] = v;
  }
  __syncthreads();
  {
    float esm2 = fmaxf(fmaxf(sRed[0], sRed[1]), fmaxf(sRed[2], sRed[3]));
    float acc2[32];
    if (t < K1_) {
      float ed_i = sED[t];
      float L = lrelu(ed_i + esm2);
      float ssum = 0.f;
      #pragma unroll
      for (int d = 0; d < 32; ++d) acc2[d] = 0.f;
      #pragma unroll
      for (int jw = 0; jw < 4; ++jw) {
        unsigned mw = sMask2[t * 5 + jw];
        const int lim = (jw < 3) ? 32 : 4;
        for (int jj = 0; jj < lim; ++jj) {
          int j = jw * 32 + jj;
          float w = 0.f;
          if ((mw >> jj) & 1u) w = __expf(lrelu(ed_i + sES[j]) - L);
          ssum += w;
          const float* hr = &sH[j * ST];          // uniform -> broadcast
          #pragma unroll
          for (int d = 0; d < 32; ++d) acc2[d] += w * hr[d];
        }
      }
      float inv = 1.f / ssum;
      #pragma unroll
      for (int d = 0; d < 32; ++d) acc2[d] = acc2[d] * inv + b2[d];
    }
    __syncthreads();               // all reads of h2a done -> overwrite with h2
    if (t < K1_) {
      #pragma unroll
      for (int d = 0; d < 32; ++d) sH[t * ST + d] = acc2[d];
    }
  }
  __syncthreads();

  // -------------- Phase F: TopK pool 2 via rank-select --------------
  {
    float npw = 0.f;
    #pragma unroll
    for (int d = 0; d < 32; ++d) npw += pw2[d] * pw2[d];
    npw = sqrtf(npw) + 1e-16f;
    if (t < K1_) {
      float dp = 0.f;
      #pragma unroll
      for (int d = 0; d < 32; ++d) dp += sH[t * ST + d] * pw2[d];
      sKey[t] = sigm(dp / npw);
    }
  }
  __syncthreads();
  if (t < K1_) {
    float sc = sKey[t];
    int rank = 0;
    for (int j = 0; j < K1_; j += 4) {
      #pragma unroll
      for (int jj = 0; jj < 4; ++jj) {
        float o = sKey[j + jj];
        rank += (o > sc || (o == sc && (j + jj) < t)) ? 1 : 0;
      }
    }
    if (rank < K2_) {
      sSel[rank] = t; sVal[rank] = sc;
      out[S2_OFF + b * K2_ + rank] = sc;
    }
  }
  __syncthreads();
  {  // xk2: reads h2 (sH rows 0..99), writes sXK rows 0..49 (sH rows 100..149) - disjoint
    int d = t & 31, r0 = t >> 5;
    for (int r = r0; r < K2_; r += 8) sXK[r * ST + d] = sH[sSel[r] * ST + d] * sVal[r];
  }
  __syncthreads();
  if (t < 32) {
    float m = -3.0e38f, s = 0.f;
    for (int r = 0; r < K2_; ++r) { float v = sXK[r * ST + t]; m = fmaxf(m, v); s += v; }
    sXV[64 + t] = m; sXV[96 + t] = s / 50.f;
  }
  __syncthreads();

  // -------------- Phase G: MLP head --------------
  const float RS = 0.99999500003749969f;   // 1/sqrt(1+1e-5)
  if (t < 32) {
    float z = fc1b[t];
    for (int k = 0; k < 128; ++k) z += sXV[k] * fc1w[k * 32 + t];
    z = fmaxf(z, 0.f);
    z = bn4g[t] * z * RS + bn4b[t];
    sKey[t] = z;
  }
  __syncthreads();
  if (t < 8) {
    float z = fc2b[t];
    for (int k = 0; k < 32; ++k) z += sKey[k] * fc2w[k * 8 + t];
    z = fmaxf(z, 0.f);
    z = bn5g[t] * z * RS + bn5b[t];
    sKey[32 + t] = z;
  }
  __syncthreads();
  if (t < 2) {
    float z = fc3b[t];
    for (int k = 0; k < 8; ++k) z += sKey[32 + k] * fc3w[k * 2 + t];
    sKey[40 + t] = z;
  }
  __syncthreads();
  if (t < 2) {
    float z0 = sKey[40], z1 = sKey[41];
    float m = fmaxf(z0, z1);
    float lse = m + logf(__expf(z0 - m) + __expf(z1 - m));
    out[b * 2 + t] = sKey[40 + t] - lse;
  }
}

extern "C" void kernel_launch(void* const* d_in, const int* in_sizes, int n_in,
                              void* d_out, int out_size, void* d_ws, size_t ws_size,
                              hipStream_t stream) {
  (void)in_sizes; (void)n_in; (void)ws_size; (void)out_size;
  const float* x    = (const float*)d_in[0];
  const float* adj  = (const float*)d_in[1];
  const float* W1   = (const float*)d_in[2];
  const float* a1s  = (const float*)d_in[3];
  const float* a1d  = (const float*)d_in[4];
  const float* b1   = (const float*)d_in[5];
  const float* W2   = (const float*)d_in[6];
  const float* a2s  = (const float*)d_in[7];
  const float* a2d  = (const float*)d_in[8];
  const float* b2   = (const float*)d_in[9];
  const float* pw1  = (const float*)d_in[10];
  const float* pw2  = (const float*)d_in[11];
  const float* fc1w = (const float*)d_in[12];
  const float* fc1b = (const float*)d_in[13];
  const float* fc2w = (const float*)d_in[14];
  const float* fc2b = (const float*)d_in[15];
  const float* fc3w = (const float*)d_in[16];
  const float* fc3b = (const float*)d_in[17];
  const float* bn4g = (const float*)d_in[18];
  const float* bn4b = (const float*)d_in[19];
  const float* bn5g = (const float*)d_in[20];
  const float* bn5b = (const float*)d_in[21];

  float*    gh    = (float*)d_ws;
  unsigned* gbits = (unsigned*)((char*)d_ws + WS_BITS_OFF);

  gnn_k1<<<B_ * 4, 256, 0, stream>>>(x, adj, W1, gh, gbits);
  gnn_k2<<<B_, 256, 0, stream>>>(gh, gbits, a1s, a1d, b1, W2, a2s, a2d, b2,
                                 pw1, pw2, fc1w, fc1b, fc2w, fc2b, fc3w, fc3b,
                                 bn4g, bn4b, bn5g, bn5b, (float*)d_out);
}

// Round 7
// 372.982 us; speedup vs baseline: 1.0731x; 1.0731x over previous
//
#include <hip/hip_runtime.h>
#include <math.h>

#define N_    200
#define B_    512
#define K1_   100
#define K2_   50
#define ST    36     // K2 sH row stride (dwords): 144B, 16B-aligned
#define XHALF 101    // K1 LDS x-half row stride (floats): bank=(5n+k)%32, <=2 lanes/bank

// out layout: logp [512*2] | s1 [512*100] | s2 [512*50]
#define S1_OFF 1024
#define S2_OFF 52224

// workspace layout (bytes):
//        0 : gh    [512][200][32] f32  = 13,107,200
// 13107200 : gbits [512][200][8]  u32  =  3,276,800   (7 words used + pad)
#define WS_BITS_OFF 13107200

__device__ __forceinline__ float lrelu(float v) { return v > 0.f ? v : 0.2f * v; }
__device__ __forceinline__ float sigm(float v)  { return 1.f / (1.f + __expf(-v)); }

// ================= K1: coalesced x@W1 (LDS-staged) + adj ballot scan =================
// grid 2048: block = (graph g = bid>>2, chunk c = bid&3) -> nodes [c*50, c*50+50)
// LDS 20.2KB + VGPR<=64 -> 8 blocks/CU = 32 waves/CU (100% occupancy)
__global__ __launch_bounds__(256, 8) void gnn_k1(
    const float* __restrict__ x, const float* __restrict__ adj,
    const float* __restrict__ W1, float* __restrict__ gh,
    unsigned* __restrict__ gbits)
{
  __shared__ float sX[50 * XHALF];   // 20,200 B
  const int bid = blockIdx.x;
  const int g = bid >> 2, c = bid & 3;
  const int t = threadIdx.x;
  const int wv = t >> 6, ln = t & 63;
  const float* ag = adj + (size_t)g * N_ * N_;

  // ---- adj>0 bitmask via ballot: coalesced 64-lane row reads (TLP hides latency) ----
  for (int r = wv; r < 50; r += 4) {
    int row = c * 50 + r;
    const float* arow = ag + row * N_;
    float a0 = arow[ln];
    float a1 = arow[64 + ln];
    float a2 = arow[128 + ln];
    float a3 = (ln < 8) ? arow[192 + ln] : -1.f;   // guard tensor OOB
    unsigned long long b0 = __ballot(a0 > 0.f);
    unsigned long long b1 = __ballot(a1 > 0.f);
    unsigned long long b2 = __ballot(a2 > 0.f);
    unsigned long long b3 = __ballot(a3 > 0.f);
    if (ln == 0) {
      unsigned* bp = gbits + (size_t)(g * N_ + row) * 8;
      *(uint4*)bp       = make_uint4((unsigned)b0, (unsigned)(b0 >> 32),
                                     (unsigned)b1, (unsigned)(b1 >> 32));
      *(uint4*)(bp + 4) = make_uint4((unsigned)b2, (unsigned)(b2 >> 32),
                                     (unsigned)b3, 0u);
    }
  }

  // ---- h = x @ W1, k-tiled (2 halves of 100) via coalesced LDS staging ----
  // chunk rows are one contiguous 40KB range: staging is lane-consecutive float4s.
  const float4* xg4 = (const float4*)(x + (size_t)g * N_ * N_);   // 50 float4 per row
  const int q = wv;                  // d-octet, wave-uniform
  float acc[8];
  #pragma unroll
  for (int d = 0; d < 8; ++d) acc[d] = 0.f;

  for (int kh = 0; kh < 2; ++kh) {
    __syncthreads();                 // previous half's readers done
    for (int f = t; f < 1250; f += 256) {   // 50 rows x 25 float4
      int r = f / 25, cc = f % 25;
      float4 v = xg4[(c * 50 + r) * 50 + kh * 25 + cc];
      float* dp = sX + r * XHALF + cc * 4;
      dp[0] = v.x; dp[1] = v.y; dp[2] = v.z; dp[3] = v.w;
    }
    __syncthreads();
    if (ln < 50) {
      const float* xr = sX + ln * XHALF;
      const float* Wq = W1 + kh * 100 * 32 + q * 8;
      #pragma unroll 4
      for (int k = 0; k < 100; ++k) {
        float xs = xr[k];
        const float* wr = Wq + k * 32;       // wave-uniform -> s_load
        #pragma unroll
        for (int d = 0; d < 8; ++d) acc[d] += xs * wr[d];
      }
    }
  }
  if (ln < 50) {
    const int node = c * 50 + ln;
    float* hp = gh + (size_t)(g * N_ + node) * 32 + q * 8;
    *(float4*)hp       = make_float4(acc[0], acc[1], acc[2], acc[3]);
    *(float4*)(hp + 4) = make_float4(acc[4], acc[5], acc[6], acc[7]);
  }
}

// ================= K2: per-graph phases B..G, all-LDS (unchanged from round 6) =================
// LDS map (bytes), total 45264:
//     0 : sH    28800  h(200xST) stage; h1 in-place; rows 100..199 = sXK; h2a/h2 rows 0..99
// 28800 : sBITS  6400
// 35200 : sW2    4096
// 39296 : sMask2 2000
// 41296 : sES     800
// 42096 : sED     800
// 42896 : sKey   1024
// 43920 : sSel    400
// 44320 : sVal    400
// 44720 : sXV     512
// 45232 : sRed     32
__global__ __launch_bounds__(256) void gnn_k2(
    const float* __restrict__ gh, const unsigned* __restrict__ gbits,
    const float* __restrict__ a1s, const float* __restrict__ a1d,
    const float* __restrict__ b1,  const float* __restrict__ W2g,
    const float* __restrict__ a2s, const float* __restrict__ a2d,
    const float* __restrict__ b2,
    const float* __restrict__ pw1, const float* __restrict__ pw2,
    const float* __restrict__ fc1w, const float* __restrict__ fc1b,
    const float* __restrict__ fc2w, const float* __restrict__ fc2b,
    const float* __restrict__ fc3w, const float* __restrict__ fc3b,
    const float* __restrict__ bn4g, const float* __restrict__ bn4b,
    const float* __restrict__ bn5g, const float* __restrict__ bn5b,
    float* __restrict__ out)
{
  __shared__ __align__(16) char smem[45264];
  float*    sH    = (float*)smem;
  float*    sXK   = sH + 100 * ST;                 // rows 100..199 of sH
  unsigned* sBITS = (unsigned*)(smem + 28800);
  float*    sW2   = (float*)(smem + 35200);
  unsigned* sMask2= (unsigned*)(smem + 39296);
  float*    sES   = (float*)(smem + 41296);
  float*    sED   = (float*)(smem + 42096);
  float*    sKey  = (float*)(smem + 42896);
  int*      sSel  = (int*)(smem + 43920);
  float*    sVal  = (float*)(smem + 44320);
  float*    sXV   = (float*)(smem + 44720);
  float*    sRed  = (float*)(smem + 45232);

  const int t = threadIdx.x;
  const int b = blockIdx.x;

  // ---- stage h (1600 float4) and bits (1600 u32), coalesced; W2 fill ----
  {
    const float4* src = (const float4*)(gh + (size_t)b * N_ * 32);
    #pragma unroll
    for (int i = 0; i < 7; ++i) {
      int j = t + i * 256;
      if (j < 1600) {
        float4 v = src[j];
        int node = j >> 3, c4 = j & 7;
        *(float4*)&sH[node * ST + c4 * 4] = v;
      }
    }
    const unsigned* bsrc = gbits + (size_t)b * N_ * 8;
    #pragma unroll
    for (int i = 0; i < 7; ++i) {
      int j = t + i * 256;
      if (j < 1600) sBITS[j] = bsrc[j];
    }
    for (int i = t; i < 1024; i += 256) sW2[i] = W2g[i];
  }
  __syncthreads();

  // ---- es/ed from staged h ----
  if (t < N_) {
    float es = 0.f, ed = 0.f;
    #pragma unroll
    for (int c = 0; c < 8; ++c) {
      float4 hv = *(const float4*)&sH[t * ST + c * 4];
      es += hv.x * a1s[c*4+0] + hv.y * a1s[c*4+1] + hv.z * a1s[c*4+2] + hv.w * a1s[c*4+3];
      ed += hv.x * a1d[c*4+0] + hv.y * a1d[c*4+1] + hv.z * a1d[c*4+2] + hv.w * a1d[c*4+3];
    }
    sES[t] = es; sED[t] = ed;
  }
  __syncthreads();

  // esmax over all nodes (safe softmax bound; leaky_relu monotone)
  {
    float v = (t < N_) ? sES[t] : -3.0e38f;
    #pragma unroll
    for (int off = 1; off < 64; off <<= 1) v = fmaxf(v, __shfl_xor(v, off, 64));
    if ((t & 63) == 0) sRed[t >> 6] = v;
  }
  __syncthreads();
  {
    float esmax = fmaxf(fmaxf(sRed[0], sRed[1]), fmaxf(sRed[2], sRed[3]));

    // -------------- Phase B: sparse masked-softmax aggregate from bit masks --------------
    float acc[32];
    if (t < N_) {
      unsigned long long m0 = (unsigned long long)sBITS[t * 8 + 0] | ((unsigned long long)sBITS[t * 8 + 1] << 32);
      unsigned long long m1 = (unsigned long long)sBITS[t * 8 + 2] | ((unsigned long long)sBITS[t * 8 + 3] << 32);
      unsigned long long m2 = (unsigned long long)sBITS[t * 8 + 4] | ((unsigned long long)sBITS[t * 8 + 5] << 32);
      unsigned long long m3 = (unsigned long long)sBITS[t * 8 + 6];
      if (t < 64)       m0 |= 1ull << t;
      else if (t < 128) m1 |= 1ull << (t - 64);
      else if (t < 192) m2 |= 1ull << (t - 128);
      else              m3 |= 1ull << (t - 192);
      float ed_i = sED[t];
      float L = lrelu(ed_i + esmax);
      float ssum = 0.f;
      #pragma unroll
      for (int d = 0; d < 32; ++d) acc[d] = 0.f;
      #define AGG(mm, base)                                                        \
        while (mm) {                                                               \
          int j = (base) + (int)__builtin_ctzll(mm); mm &= (mm - 1);               \
          float w = __expf(lrelu(ed_i + sES[j]) - L); ssum += w;                   \
          const float* hr = &sH[j * ST];                                           \
          _Pragma("unroll")                                                        \
          for (int c = 0; c < 8; ++c) {                                            \
            float4 hv = *(const float4*)(hr + c * 4);                              \
            acc[c*4+0] += w * hv.x; acc[c*4+1] += w * hv.y;                        \
            acc[c*4+2] += w * hv.z; acc[c*4+3] += w * hv.w;                        \
          }                                                                        \
        }
      AGG(m0, 0) AGG(m1, 64) AGG(m2, 128) AGG(m3, 192)
      #undef AGG
      float inv = 1.f / ssum;
      #pragma unroll
      for (int d = 0; d < 32; ++d) acc[d] = acc[d] * inv + b1[d];
    }
    __syncthreads();                 // all reads of h done -> overwrite with h1
    if (t < N_) {
      #pragma unroll
      for (int d = 0; d < 32; ++d) sH[t * ST + d] = acc[d];
    }
  }
  __syncthreads();

  // -------------- Phase C: TopK pool 1 via barrier-free rank-select --------------
  {
    float npw = 0.f;
    #pragma unroll
    for (int d = 0; d < 32; ++d) npw += pw1[d] * pw1[d];
    npw = sqrtf(npw) + 1e-16f;
    float sc = -1.f;
    if (t < N_) {
      float dp = 0.f;
      #pragma unroll
      for (int d = 0; d < 32; ++d) dp += sH[t * ST + d] * pw1[d];
      sc = sigm(dp / npw);
    }
    sKey[t] = sc;
  }
  __syncthreads();
  if (t < N_) {
    float sc = sKey[t];
    int rank = 0;
    for (int j = 0; j < N_; j += 4) {
      #pragma unroll
      for (int jj = 0; jj < 4; ++jj) {
        float o = sKey[j + jj];                       // uniform -> broadcast
        rank += (o > sc || (o == sc && (j + jj) < t)) ? 1 : 0;
      }
    }
    if (rank < K1_) {                                 // stable desc order == lax.top_k
      sSel[rank] = t; sVal[rank] = sc;
      out[S1_OFF + b * K1_ + rank] = sc;
    }
  }
  __syncthreads();
  // xk = h1[sel]*val. Dest (sH rows 100..199) aliases source rows -> reg staging.
  {
    float tmp[13];
    #pragma unroll
    for (int it = 0; it < 13; ++it) {
      int i = t + it * 256;
      if (i < K1_ * 32) tmp[it] = sH[sSel[i >> 5] * ST + (i & 31)] * sVal[i >> 5];
    }
    __syncthreads();
    #pragma unroll
    for (int it = 0; it < 13; ++it) {
      int i = t + it * 256;
      if (i < K1_ * 32) sXK[(i >> 5) * ST + (i & 31)] = tmp[it];
    }
  }
  __syncthreads();
  // x1 = [max, mean] over 100 pooled nodes
  if (t < 32) {
    float m = -3.0e38f, s = 0.f;
    for (int r = 0; r < K1_; ++r) { float v = sXK[r * ST + t]; m = fmaxf(m, v); s += v; }
    sXV[t] = m; sXV[32 + t] = s / 100.f;
  }

  // -------------- Phase D: 2-hop mask (a2 != 0 | eye), boolean bitsets --------------
  if (t < K1_) {
    int gi = sSel[t];
    #pragma unroll
    for (int w = 0; w < 4; ++w) {
      unsigned m = 0;
      const int lim = (w < 3) ? 32 : 4;
      for (int jj = 0; jj < lim; ++jj) {
        int j = w * 32 + jj;
        int gj = sSel[j];
        unsigned bit = (sBITS[gi * 8 + (gj >> 5)] >> (gj & 31)) & 1u;
        if (j == t) bit = 1u;                       // (A+I) self loop
        m |= bit << jj;
      }
      sMask2[t * 5 + w] = m;
    }
  }
  __syncthreads();
  {
    unsigned pr0 = 0, pr1 = 0, pr2 = 0, pr3 = 0;
    if (t < K1_) {
      #pragma unroll
      for (int kw = 0; kw < 4; ++kw) {
        unsigned mk = sMask2[t * 5 + kw];
        const int lim = (kw < 3) ? 32 : 4;
        for (int kk = 0; kk < lim; ++kk) {
          if ((mk >> kk) & 1u) {
            int k = kw * 32 + kk;
            pr0 |= sMask2[k * 5 + 0]; pr1 |= sMask2[k * 5 + 1];
            pr2 |= sMask2[k * 5 + 2]; pr3 |= sMask2[k * 5 + 3];
          }
        }
      }
    }
    __syncthreads();
    if (t < K1_) {
      sMask2[t * 5 + 0] = pr0; sMask2[t * 5 + 1] = pr1;
      sMask2[t * 5 + 2] = pr2; sMask2[t * 5 + 3] = pr3;
    }
  }
  __syncthreads();

  // -------------- Phase E: GAT2 --------------
  // h2a = xk @ W2 -> sH rows 0..99 (h1 rows 0..99 dead; xk rows 100..199 untouched)
  if (t < K1_) {
    float xk[32];
    #pragma unroll
    for (int c = 0; c < 8; ++c) *(float4*)&xk[c * 4] = *(const float4*)&sXK[t * ST + c * 4];
    float acc2[32];
    #pragma unroll
    for (int d = 0; d < 32; ++d) acc2[d] = 0.f;
    #pragma unroll
    for (int k = 0; k < 32; ++k) {
      float xv = xk[k];
      const float* wr = &sW2[k * 32];
      #pragma unroll
      for (int d = 0; d < 32; ++d) acc2[d] += xv * wr[d];
    }
    float es = 0.f, ed = 0.f;
    #pragma unroll
    for (int d = 0; d < 32; ++d) { es += acc2[d] * a2s[d]; ed += acc2[d] * a2d[d]; }
    sES[t] = es; sED[t] = ed;
    #pragma unroll
    for (int d = 0; d < 32; ++d) sH[t * ST + d] = acc2[d];
  }
  __syncthreads();
  {
    float v = (t < K1_) ? sES[t] : -3.0e38f;
    #pragma unroll
    for (int off = 1; off < 64; off <<= 1) v = fmaxf(v, __shfl_xor(v, off, 64));
    if ((t & 63) == 0) sRed[t >> 6] = v;
  }
  __syncthreads();
  {
    float esm2 = fmaxf(fmaxf(sRed[0], sRed[1]), fmaxf(sRed[2], sRed[3]));
    float acc2[32];
    if (t < K1_) {
      float ed_i = sED[t];
      float L = lrelu(ed_i + esm2);
      float ssum = 0.f;
      #pragma unroll
      for (int d = 0; d < 32; ++d) acc2[d] = 0.f;
      #pragma unroll
      for (int jw = 0; jw < 4; ++jw) {
        unsigned mw = sMask2[t * 5 + jw];
        const int lim = (jw < 3) ? 32 : 4;
        for (int jj = 0; jj < lim; ++jj) {
          int j = jw * 32 + jj;
          float w = 0.f;
          if ((mw >> jj) & 1u) w = __expf(lrelu(ed_i + sES[j]) - L);
          ssum += w;
          const float* hr = &sH[j * ST];          // uniform -> broadcast
          #pragma unroll
          for (int d = 0; d < 32; ++d) acc2[d] += w * hr[d];
        }
      }
      float inv = 1.f / ssum;
      #pragma unroll
      for (int d = 0; d < 32; ++d) acc2[d] = acc2[d] * inv + b2[d];
    }
    __syncthreads();               // all reads of h2a done -> overwrite with h2
    if (t < K1_) {
      #pragma unroll
      for (int d = 0; d < 32; ++d) sH[t * ST + d] = acc2[d];
    }
  }
  __syncthreads();

  // -------------- Phase F: TopK pool 2 via rank-select --------------
  {
    float npw = 0.f;
    #pragma unroll
    for (int d = 0; d < 32; ++d) npw += pw2[d] * pw2[d];
    npw = sqrtf(npw) + 1e-16f;
    if (t < K1_) {
      float dp = 0.f;
      #pragma unroll
      for (int d = 0; d < 32; ++d) dp += sH[t * ST + d] * pw2[d];
      sKey[t] = sigm(dp / npw);
    }
  }
  __syncthreads();
  if (t < K1_) {
    float sc = sKey[t];
    int rank = 0;
    for (int j = 0; j < K1_; j += 4) {
      #pragma unroll
      for (int jj = 0; jj < 4; ++jj) {
        float o = sKey[j + jj];
        rank += (o > sc || (o == sc && (j + jj) < t)) ? 1 : 0;
      }
    }
    if (rank < K2_) {
      sSel[rank] = t; sVal[rank] = sc;
      out[S2_OFF + b * K2_ + rank] = sc;
    }
  }
  __syncthreads();
  {  // xk2: reads h2 (sH rows 0..99), writes sXK rows 0..49 (sH rows 100..149) - disjoint
    int d = t & 31, r0 = t >> 5;
    for (int r = r0; r < K2_; r += 8) sXK[r * ST + d] = sH[sSel[r] * ST + d] * sVal[r];
  }
  __syncthreads();
  if (t < 32) {
    float m = -3.0e38f, s = 0.f;
    for (int r = 0; r < K2_; ++r) { float v = sXK[r * ST + t]; m = fmaxf(m, v); s += v; }
    sXV[64 + t] = m; sXV[96 + t] = s / 50.f;
  }
  __syncthreads();

  // -------------- Phase G: MLP head --------------
  const float RS = 0.99999500003749969f;   // 1/sqrt(1+1e-5)
  if (t < 32) {
    float z = fc1b[t];
    for (int k = 0; k < 128; ++k) z += sXV[k] * fc1w[k * 32 + t];
    z = fmaxf(z, 0.f);
    z = bn4g[t] * z * RS + bn4b[t];
    sKey[t] = z;
  }
  __syncthreads();
  if (t < 8) {
    float z = fc2b[t];
    for (int k = 0; k < 32; ++k) z += sKey[k] * fc2w[k * 8 + t];
    z = fmaxf(z, 0.f);
    z = bn5g[t] * z * RS + bn5b[t];
    sKey[32 + t] = z;
  }
  __syncthreads();
  if (t < 2) {
    float z = fc3b[t];
    for (int k = 0; k < 8; ++k) z += sKey[32 + k] * fc3w[k * 2 + t];
    sKey[40 + t] = z;
  }
  __syncthreads();
  if (t < 2) {
    float z0 = sKey[40], z1 = sKey[41];
    float m = fmaxf(z0, z1);
    float lse = m + logf(__expf(z0 - m) + __expf(z1 - m));
    out[b * 2 + t] = sKey[40 + t] - lse;
  }
}

extern "C" void kernel_launch(void* const* d_in, const int* in_sizes, int n_in,
                              void* d_out, int out_size, void* d_ws, size_t ws_size,
                              hipStream_t stream) {
  (void)in_sizes; (void)n_in; (void)ws_size; (void)out_size;
  const float* x    = (const float*)d_in[0];
  const float* adj  = (const float*)d_in[1];
  const float* W1   = (const float*)d_in[2];
  const float* a1s  = (const float*)d_in[3];
  const float* a1d  = (const float*)d_in[4];
  const float* b1   = (const float*)d_in[5];
  const float* W2   = (const float*)d_in[6];
  const float* a2s  = (const float*)d_in[7];
  const float* a2d  = (const float*)d_in[8];
  const float* b2   = (const float*)d_in[9];
  const float* pw1  = (const float*)d_in[10];
  const float* pw2  = (const float*)d_in[11];
  const float* fc1w = (const float*)d_in[12];
  const float* fc1b = (const float*)d_in[13];
  const float* fc2w = (const float*)d_in[14];
  const float* fc2b = (const float*)d_in[15];
  const float* fc3w = (const float*)d_in[16];
  const float* fc3b = (const float*)d_in[17];
  const float* bn4g = (const float*)d_in[18];
  const float* bn4b = (const float*)d_in[19];
  const float* bn5g = (const float*)d_in[20];
  const float* bn5b = (const float*)d_in[21];

  float*    gh    = (float*)d_ws;
  unsigned* gbits = (unsigned*)((char*)d_ws + WS_BITS_OFF);

  gnn_k1<<<B_ * 4, 256, 0, stream>>>(x, adj, W1, gh, gbits);
  gnn_k2<<<B_, 256, 0, stream>>>(gh, gbits, a1s, a1d, b1, W2, a2s, a2d, b2,
                                 pw1, pw2, fc1w, fc1b, fc2w, fc2b, fc3w, fc3b,
                                 bn4g, bn4b, bn5g, bn5b, (float*)d_out);
}